// Round 1
// baseline (1145.628 us; speedup 1.0000x reference)
//
#include <hip/hip_runtime.h>
#include <math.h>

// Problem constants (from reference)
#define NN 20000      // nodes
#define EE 640000     // edges
#define HH 2          // heads
#define DD 64         // dim
#define LL 4          // layers
#define HD 128        // H*D

// ---------------- CSR build ----------------

__global__ void hist_kernel(const int* __restrict__ dst, int* __restrict__ deg) {
    int e = blockIdx.x * 256 + threadIdx.x;
    if (e < EE) atomicAdd(&deg[dst[e]], 1);
}

// single-block exclusive scan of deg[0..n) -> offsets[0..n], offsets[n]=total
__global__ void scan_kernel(const int* __restrict__ deg, int* __restrict__ offsets, int n) {
    __shared__ int buf[256];
    __shared__ int carry;
    if (threadIdx.x == 0) carry = 0;
    __syncthreads();
    for (int base = 0; base < n; base += 256) {
        int i = base + threadIdx.x;
        int v = (i < n) ? deg[i] : 0;
        buf[threadIdx.x] = v;
        __syncthreads();
        for (int off = 1; off < 256; off <<= 1) {
            int t = (threadIdx.x >= off) ? buf[threadIdx.x - off] : 0;
            __syncthreads();
            buf[threadIdx.x] += t;
            __syncthreads();
        }
        int incl = buf[threadIdx.x];
        if (i < n) offsets[i] = carry + (incl - v);
        __syncthreads();
        if (threadIdx.x == 255) carry += buf[255];
        __syncthreads();
    }
    if (threadIdx.x == 0) offsets[n] = carry;
}

__global__ void scatter_kernel(const int* __restrict__ src, const int* __restrict__ dst,
                               const int* __restrict__ offsets, int* __restrict__ cursor,
                               int* __restrict__ csr_src, int* __restrict__ csr_eid) {
    int e = blockIdx.x * 256 + threadIdx.x;
    if (e >= EE) return;
    int d = dst[e];
    int pos = offsets[d] + atomicAdd(&cursor[d], 1);
    csr_src[pos] = src[e];
    csr_eid[pos] = e;
}

// ---------------- per-layer kernels ----------------

// xl = x@Wl + bl ; xr = x@Wr + br  ([N,64] x [64,128])
// 16 rows per block, 128 threads (thread j = output column)
__global__ void gemm_lr(const float* __restrict__ x,
                        const float* __restrict__ Wl, const float* __restrict__ bl,
                        const float* __restrict__ Wr, const float* __restrict__ br,
                        float* __restrict__ xl, float* __restrict__ xr) {
    __shared__ float xs[16][DD];
    int row0 = blockIdx.x * 16;
    for (int t = threadIdx.x; t < 16 * DD; t += 128) {
        xs[t >> 6][t & 63] = x[row0 * DD + t];
    }
    __syncthreads();
    int j = threadIdx.x;
    float accl[16], accr[16];
    float blv = bl[j], brv = br[j];
#pragma unroll
    for (int r = 0; r < 16; ++r) { accl[r] = blv; accr[r] = brv; }
    for (int k = 0; k < DD; ++k) {
        float wl = Wl[k * HD + j];
        float wr = Wr[k * HD + j];
#pragma unroll
        for (int r = 0; r < 16; ++r) {
            float xv = xs[r][k];
            accl[r] += xv * wl;
            accr[r] += xv * wr;
        }
    }
#pragma unroll
    for (int r = 0; r < 16; ++r) {
        xl[(row0 + r) * HD + j] = accl[r];
        xr[(row0 + r) * HD + j] = accr[r];
    }
}

// one wave per edge, both heads; lane = feature dim
__global__ void edge_logits_kernel(const int* __restrict__ src, const int* __restrict__ dst,
                                   const float* __restrict__ xl, const float* __restrict__ xr,
                                   const float* __restrict__ att, float* __restrict__ logits) {
    int wid = (blockIdx.x * 256 + threadIdx.x) >> 6;   // edge id
    int lane = threadIdx.x & 63;
    if (wid >= EE) return;
    int s = src[wid], t = dst[wid];
    const float* xls = xl + (long)s * HD;
    const float* xrt = xr + (long)t * HD;
    float v0 = xls[lane] + xrt[lane];
    float v1 = xls[64 + lane] + xrt[64 + lane];
    v0 = v0 > 0.f ? v0 : 0.2f * v0;
    v1 = v1 > 0.f ? v1 : 0.2f * v1;
    v0 *= att[lane];
    v1 *= att[64 + lane];
#pragma unroll
    for (int off = 32; off >= 1; off >>= 1) {
        v0 += __shfl_xor(v0, off);
        v1 += __shfl_xor(v1, off);
    }
    if (lane == 0) {
        logits[wid * 2 + 0] = v0;
        logits[wid * 2 + 1] = v1;
    }
}

// one block per node; wave 0 = head 0, wave 1 = head 1; lane = feature dim
__global__ void aggregate_kernel(const float* __restrict__ logits, const float* __restrict__ xl,
                                 const int* __restrict__ offsets, const int* __restrict__ csr_src,
                                 const int* __restrict__ csr_eid, const float* __restrict__ bias,
                                 float* __restrict__ xout) {
    int node = blockIdx.x;
    int h = threadIdx.x >> 6;
    int lane = threadIdx.x & 63;
    int start = offsets[node];
    int deg = offsets[node + 1] - start;

    // phase 1: segment max of logits
    float m = -INFINITY;
    for (int i = lane; i < deg; i += 64) {
        int eid = csr_eid[start + i];
        m = fmaxf(m, logits[eid * 2 + h]);
    }
#pragma unroll
    for (int off = 32; off >= 1; off >>= 1) m = fmaxf(m, __shfl_xor(m, off));

    // phase 2: denom = sum exp(logit - m)
    float ssum = 0.f;
    for (int i = lane; i < deg; i += 64) {
        int eid = csr_eid[start + i];
        ssum += __expf(logits[eid * 2 + h] - m);
    }
#pragma unroll
    for (int off = 32; off >= 1; off >>= 1) ssum += __shfl_xor(ssum, off);
    float inv = 1.0f / (ssum + 1e-16f);

    // phase 3: out = sum alpha * xl[src]
    float acc = 0.f;
    for (int i = 0; i < deg; ++i) {
        int eid = csr_eid[start + i];
        int s = csr_src[start + i];
        float w = __expf(logits[eid * 2 + h] - m) * inv;
        acc += w * xl[(long)s * HD + h * 64 + lane];
    }

    __shared__ float hacc[HH][DD];
    hacc[h][lane] = acc;
    __syncthreads();
    if (threadIdx.x < 64) {
        float r = 0.5f * (hacc[0][lane] + hacc[1][lane]) + bias[lane];
        r = r > 0.f ? r : 0.01f * r;
        xout[node * DD + lane] = r;
    }
}

// out = leaky_relu(x @ Wo + bo, 0.01); 16 rows/block, 64 threads
__global__ void final_gemm(const float* __restrict__ x, const float* __restrict__ Wo,
                           const float* __restrict__ bo, float* __restrict__ out) {
    __shared__ float xs[16][DD];
    int row0 = blockIdx.x * 16;
    for (int t = threadIdx.x; t < 16 * DD; t += 64) {
        xs[t >> 6][t & 63] = x[row0 * DD + t];
    }
    __syncthreads();
    int j = threadIdx.x;
    float acc[16];
    float bv = bo[j];
#pragma unroll
    for (int r = 0; r < 16; ++r) acc[r] = bv;
    for (int k = 0; k < DD; ++k) {
        float w = Wo[k * DD + j];
#pragma unroll
        for (int r = 0; r < 16; ++r) acc[r] += xs[r][k] * w;
    }
#pragma unroll
    for (int r = 0; r < 16; ++r) {
        float v = acc[r];
        v = v > 0.f ? v : 0.01f * v;
        out[(row0 + r) * DD + j] = v;
    }
}

extern "C" void kernel_launch(void* const* d_in, const int* in_sizes, int n_in,
                              void* d_out, int out_size, void* d_ws, size_t ws_size,
                              hipStream_t stream) {
    const int* edge_index = (const int*)d_in[0];
    const int* src = edge_index;
    const int* dst = edge_index + EE;
    // d_in[1] = edge_weight, unused
    const float* pert = (const float*)d_in[2];
    const float* Wl = (const float*)d_in[3];
    const float* bl = (const float*)d_in[4];
    const float* Wr = (const float*)d_in[5];
    const float* br = (const float*)d_in[6];
    const float* att = (const float*)d_in[7];
    const float* bias = (const float*)d_in[8];
    const float* Wo = (const float*)d_in[9];
    const float* bo = (const float*)d_in[10];
    float* out = (float*)d_out;

    // workspace carve-up
    char* w = (char*)d_ws;
    float* xl = (float*)w;            w += (size_t)NN * HD * 4;
    float* xr = (float*)w;            w += (size_t)NN * HD * 4;
    float* logits = (float*)w;        w += (size_t)EE * HH * 4;
    float* xb0 = (float*)w;           w += (size_t)NN * DD * 4;
    float* xb1 = (float*)w;           w += (size_t)NN * DD * 4;
    int* deg = (int*)w;               w += (size_t)NN * 4;
    int* offsets = (int*)w;           w += (size_t)(NN + 1) * 4 + 4; // keep alignment
    int* cursor = (int*)w;            w += (size_t)NN * 4;
    int* csr_src = (int*)w;           w += (size_t)EE * 4;
    int* csr_eid = (int*)w;           w += (size_t)EE * 4;

    // CSR build (dst is layer-invariant; built once per launch)
    hipMemsetAsync(deg, 0, (size_t)NN * 4, stream);
    hipMemsetAsync(cursor, 0, (size_t)NN * 4, stream);
    hist_kernel<<<(EE + 255) / 256, 256, 0, stream>>>(dst, deg);
    scan_kernel<<<1, 256, 0, stream>>>(deg, offsets, NN);
    scatter_kernel<<<(EE + 255) / 256, 256, 0, stream>>>(src, dst, offsets, cursor, csr_src, csr_eid);

    const float* xin = pert;
    float* bufs[2] = {xb0, xb1};
    for (int l = 0; l < LL; ++l) {
        gemm_lr<<<NN / 16, 128, 0, stream>>>(xin, Wl + (size_t)l * DD * HD, bl + (size_t)l * HD,
                                             Wr + (size_t)l * DD * HD, br + (size_t)l * HD, xl, xr);
        edge_logits_kernel<<<(EE * 64 + 255) / 256, 256, 0, stream>>>(src, dst, xl, xr,
                                                                      att + (size_t)l * HD, logits);
        aggregate_kernel<<<NN, 128, 0, stream>>>(logits, xl, offsets, csr_src, csr_eid,
                                                 bias + (size_t)l * DD, bufs[l & 1]);
        xin = bufs[l & 1];
    }
    final_gemm<<<NN / 16, 64, 0, stream>>>(xin, Wo, bo, out);
}

// Round 2
// 815.405 us; speedup vs baseline: 1.4050x; 1.4050x over previous
//
#include <hip/hip_runtime.h>
#include <math.h>

// Problem constants (from reference)
#define NN 20000      // nodes
#define EE 640000     // edges
#define HH 2          // heads
#define DD 64         // dim
#define LL 4          // layers
#define HD 128        // H*D

// ---------------- CSR build ----------------

__global__ void hist_kernel(const int* __restrict__ dst, int* __restrict__ deg) {
    int e = blockIdx.x * 256 + threadIdx.x;
    if (e < EE) atomicAdd(&deg[dst[e]], 1);
}

// single-block exclusive scan of deg[0..n) -> offsets[0..n], offsets[n]=total
__global__ void scan_kernel(const int* __restrict__ deg, int* __restrict__ offsets, int n) {
    __shared__ int buf[256];
    __shared__ int carry;
    if (threadIdx.x == 0) carry = 0;
    __syncthreads();
    for (int base = 0; base < n; base += 256) {
        int i = base + threadIdx.x;
        int v = (i < n) ? deg[i] : 0;
        buf[threadIdx.x] = v;
        __syncthreads();
        for (int off = 1; off < 256; off <<= 1) {
            int t = (threadIdx.x >= off) ? buf[threadIdx.x - off] : 0;
            __syncthreads();
            buf[threadIdx.x] += t;
            __syncthreads();
        }
        int incl = buf[threadIdx.x];
        if (i < n) offsets[i] = carry + (incl - v);
        __syncthreads();
        if (threadIdx.x == 255) carry += buf[255];
        __syncthreads();
    }
    if (threadIdx.x == 0) offsets[n] = carry;
}

__global__ void scatter_kernel(const int* __restrict__ src, const int* __restrict__ dst,
                               const int* __restrict__ offsets, int* __restrict__ cursor,
                               int* __restrict__ csr_src) {
    int e = blockIdx.x * 256 + threadIdx.x;
    if (e >= EE) return;
    int d = dst[e];
    int pos = offsets[d] + atomicAdd(&cursor[d], 1);
    csr_src[pos] = src[e];
}

// ---------------- per-layer kernels ----------------

// xl = x@Wl + bl ; xr = x@Wr + br  ([N,64] x [64,128])
// 16 rows per block, 128 threads (thread j = output column)
__global__ void gemm_lr(const float* __restrict__ x,
                        const float* __restrict__ Wl, const float* __restrict__ bl,
                        const float* __restrict__ Wr, const float* __restrict__ br,
                        float* __restrict__ xl, float* __restrict__ xr) {
    __shared__ float xs[16][DD];
    int row0 = blockIdx.x * 16;
    for (int t = threadIdx.x; t < 16 * DD; t += 128) {
        xs[t >> 6][t & 63] = x[row0 * DD + t];
    }
    __syncthreads();
    int j = threadIdx.x;
    float accl[16], accr[16];
    float blv = bl[j], brv = br[j];
#pragma unroll
    for (int r = 0; r < 16; ++r) { accl[r] = blv; accr[r] = brv; }
    for (int k = 0; k < DD; ++k) {
        float wl = Wl[k * HD + j];
        float wr = Wr[k * HD + j];
#pragma unroll
        for (int r = 0; r < 16; ++r) {
            float xv = xs[r][k];
            accl[r] += xv * wl;
            accr[r] += xv * wr;
        }
    }
#pragma unroll
    for (int r = 0; r < 16; ++r) {
        xl[(row0 + r) * HD + j] = accl[r];
        xr[(row0 + r) * HD + j] = accr[r];
    }
}

// Fused GATv2 edge phase: logits + online softmax + weighted aggregation.
// One block per dst node; wave 0 = head 0, wave 1 = head 1; lane = feature dim.
// xl[src] is gathered exactly once per edge and reused for logit + message.
__global__ void fused_aggregate(const float* __restrict__ xl, const float* __restrict__ xr,
                                const float* __restrict__ att, const int* __restrict__ offsets,
                                const int* __restrict__ csr_src, const float* __restrict__ bias,
                                float* __restrict__ xout) {
    int node = blockIdx.x;
    int h = threadIdx.x >> 6;
    int lane = threadIdx.x & 63;
    int start = offsets[node];
    int deg = offsets[node + 1] - start;

    float xrv = xr[(long)node * HD + h * 64 + lane];
    float attv = att[h * 64 + lane];

    float m = -INFINITY;   // running max (wave-uniform after reduce)
    float ssum = 0.f;      // running softmax denom
    float acc = 0.f;       // running weighted message (per lane)

    for (int base = 0; base < deg; base += 64) {
        int cnt = min(64, deg - base);
        // batch-load up to 64 src indices, broadcast via shuffle
        int batch = (base + lane < deg) ? csr_src[start + base + lane] : 0;

        int s0 = __shfl(batch, 0);
        float xlv = xl[(long)s0 * HD + h * 64 + lane];
        for (int j = 0; j < cnt; ++j) {
            float xlv_next = 0.f;
            if (j + 1 < cnt) {   // wave-uniform; prefetch next edge's gather
                int s1 = __shfl(batch, j + 1);
                xlv_next = xl[(long)s1 * HD + h * 64 + lane];
            }
            float v = xlv + xrv;
            v = v > 0.f ? v : 0.2f * v;   // leaky_relu(0.2)
            v *= attv;
#pragma unroll
            for (int off = 32; off >= 1; off >>= 1) v += __shfl_xor(v, off);
            // online softmax update (v is wave-uniform)
            float mn = fmaxf(m, v);
            float c = __expf(m - mn);     // exp(-inf)=0 handles first edge
            float wgt = __expf(v - mn);
            ssum = ssum * c + wgt;
            acc = acc * c + wgt * xlv;
            m = mn;
            xlv = xlv_next;
        }
    }

    float r = acc / (ssum + 1e-16f);      // deg==0 -> 0

    __shared__ float hacc[HH][DD];
    hacc[h][lane] = r;
    __syncthreads();
    if (threadIdx.x < 64) {
        float o = 0.5f * (hacc[0][lane] + hacc[1][lane]) + bias[lane];
        o = o > 0.f ? o : 0.01f * o;      // leaky_relu(0.01)
        xout[node * DD + lane] = o;
    }
}

// out = leaky_relu(x @ Wo + bo, 0.01); 16 rows/block, 64 threads
__global__ void final_gemm(const float* __restrict__ x, const float* __restrict__ Wo,
                           const float* __restrict__ bo, float* __restrict__ out) {
    __shared__ float xs[16][DD];
    int row0 = blockIdx.x * 16;
    for (int t = threadIdx.x; t < 16 * DD; t += 64) {
        xs[t >> 6][t & 63] = x[row0 * DD + t];
    }
    __syncthreads();
    int j = threadIdx.x;
    float acc[16];
    float bv = bo[j];
#pragma unroll
    for (int r = 0; r < 16; ++r) acc[r] = bv;
    for (int k = 0; k < DD; ++k) {
        float w = Wo[k * DD + j];
#pragma unroll
        for (int r = 0; r < 16; ++r) acc[r] += xs[r][k] * w;
    }
#pragma unroll
    for (int r = 0; r < 16; ++r) {
        float v = acc[r];
        v = v > 0.f ? v : 0.01f * v;
        out[(row0 + r) * DD + j] = v;
    }
}

extern "C" void kernel_launch(void* const* d_in, const int* in_sizes, int n_in,
                              void* d_out, int out_size, void* d_ws, size_t ws_size,
                              hipStream_t stream) {
    const int* edge_index = (const int*)d_in[0];
    const int* src = edge_index;
    const int* dst = edge_index + EE;
    // d_in[1] = edge_weight, unused
    const float* pert = (const float*)d_in[2];
    const float* Wl = (const float*)d_in[3];
    const float* bl = (const float*)d_in[4];
    const float* Wr = (const float*)d_in[5];
    const float* br = (const float*)d_in[6];
    const float* att = (const float*)d_in[7];
    const float* bias = (const float*)d_in[8];
    const float* Wo = (const float*)d_in[9];
    const float* bo = (const float*)d_in[10];
    float* out = (float*)d_out;

    // workspace carve-up
    char* w = (char*)d_ws;
    float* xl = (float*)w;            w += (size_t)NN * HD * 4;
    float* xr = (float*)w;            w += (size_t)NN * HD * 4;
    float* xb0 = (float*)w;           w += (size_t)NN * DD * 4;
    float* xb1 = (float*)w;           w += (size_t)NN * DD * 4;
    int* deg = (int*)w;               w += (size_t)NN * 4;
    int* offsets = (int*)w;           w += (size_t)(NN + 1) * 4 + 4; // keep alignment
    int* cursor = (int*)w;            w += (size_t)NN * 4;
    int* csr_src = (int*)w;           w += (size_t)EE * 4;

    // CSR build (dst is layer-invariant; built once per launch)
    hipMemsetAsync(deg, 0, (size_t)NN * 4, stream);
    hipMemsetAsync(cursor, 0, (size_t)NN * 4, stream);
    hist_kernel<<<(EE + 255) / 256, 256, 0, stream>>>(dst, deg);
    scan_kernel<<<1, 256, 0, stream>>>(deg, offsets, NN);
    scatter_kernel<<<(EE + 255) / 256, 256, 0, stream>>>(src, dst, offsets, cursor, csr_src);

    const float* xin = pert;
    float* bufs[2] = {xb0, xb1};
    for (int l = 0; l < LL; ++l) {
        gemm_lr<<<NN / 16, 128, 0, stream>>>(xin, Wl + (size_t)l * DD * HD, bl + (size_t)l * HD,
                                             Wr + (size_t)l * DD * HD, br + (size_t)l * HD, xl, xr);
        fused_aggregate<<<NN, 128, 0, stream>>>(xl, xr, att + (size_t)l * HD, offsets,
                                                csr_src, bias + (size_t)l * DD, bufs[l & 1]);
        xin = bufs[l & 1];
    }
    final_gemm<<<NN / 16, 64, 0, stream>>>(xin, Wo, bo, out);
}